// Round 1
// baseline (131.842 us; speedup 1.0000x reference)
//
#include <hip/hip_runtime.h>
#include <hip/hip_bf16.h>

// Problem constants (fixed shapes from the reference)
#define DIN   2048
#define DOUT  2048
#define NTOK  2048
#define NE    8
#define TOPK  2
#define NK    (NTOK*TOPK)   // 4096 flat (token,slot) rows
#define BM    128
#define BN    128
#define BK    64
#define KTILES (DIN/BK)     // 32
#define MAXMT  (NK/BM + NE) // 40 worst-case M-tiles across ragged experts

typedef __attribute__((ext_vector_type(8))) short bf16x8;
typedef __attribute__((ext_vector_type(4))) float f32x4;

__device__ inline unsigned short f2bf(float f) {
    union { float f; unsigned u; } v; v.f = f;
    unsigned r = v.u + 0x7FFF + ((v.u >> 16) & 1);   // RTNE
    return (unsigned short)(r >> 16);
}
__device__ inline unsigned pack2(float a, float b) {
    return (unsigned)f2bf(a) | ((unsigned)f2bf(b) << 16);
}

// Grouped GEMM over sorted-by-expert rows. One block = 128 sorted rows x 128 d_out cols.
// A-rows gathered via sorted_scattered_idxs; epilogue atomically adds gate*y into out[token].
__global__ __launch_bounds__(256, 2) void moe_gemm(
    const float* __restrict__ inputs,        // [NTOK, DIN]
    const float* __restrict__ weight,        // [NE, DOUT, DIN]
    const int*   __restrict__ sorted_scattered_idxs, // [NK]
    const int*   __restrict__ expert_offsets,        // [NE] cumsum ends
    const float* __restrict__ gates,         // [NTOK, TOPK] flat: gates[p]
    float*       __restrict__ out)           // [NTOK, DOUT]
{
    __shared__ unsigned short As[BM * BK];   // XOR-swizzled bf16 tiles
    __shared__ unsigned short Bs[BN * BK];
    __shared__ int   s_tok[BM];
    __shared__ float s_gate[BM];

    const int mt = blockIdx.y;
    const int n0 = blockIdx.x * BN;

    // Resolve this M-tile: which expert, which sorted-row range
    int e = -1, m0 = 0, cnt = 0;
    {
        int acc = 0, prev = 0;
        for (int i = 0; i < NE; ++i) {
            int end = expert_offsets[i];
            int c = end - prev;
            int t = (c + BM - 1) / BM;
            if (mt < acc + t) {
                e = i; m0 = prev + (mt - acc) * BM;
                cnt = end - m0; if (cnt > BM) cnt = BM;
                break;
            }
            acc += t; prev = end;
        }
    }
    if (e < 0) return;   // tail blocks beyond the real tile count

    const int tid = threadIdx.x;
    if (tid < BM) {
        int idx = (tid < cnt) ? (m0 + tid) : m0;   // clamp ragged rows to a valid gather
        int p = sorted_scattered_idxs[idx];        // flat slot id = token*TOPK + slot
        s_tok[tid]  = p;
        s_gate[tid] = gates[p];
    }
    __syncthreads();

    const int wid = tid >> 6, lane = tid & 63;
    const int wm = (wid >> 1) * 64, wn = (wid & 1) * 64;  // 2x2 waves, 64x64 each
    const int g  = lane >> 4, lr = lane & 15;

    f32x4 acc[4][4];
    #pragma unroll
    for (int i = 0; i < 4; ++i)
        #pragma unroll
        for (int j = 0; j < 4; ++j) acc[i][j] = (f32x4)0.0f;

    const float* wbase = weight + (size_t)e * DOUT * DIN;

    for (int kt = 0; kt < KTILES; ++kt) {
        const int kof = kt * BK;
        __syncthreads();   // previous iter's readers done before overwrite
        // Stage A (gathered rows) and B (weight rows), fused fp32->bf16 cvt.
        // 1024 16B-chunks per tile; 256 threads x 4 chunks.
        #pragma unroll
        for (int i = 0; i < 4; ++i) {
            int c   = tid + i * 256;
            int row = c >> 3, ch = c & 7;
            int sch = ch ^ (row & 7);            // 16B-chunk XOR swizzle
            // --- A ---
            {
                int t = s_tok[row] >> 1;         // token id
                const float4* src = (const float4*)(inputs + (size_t)t * DIN + kof + ch * 8);
                float4 f0 = src[0], f1 = src[1];
                uint4 pk;
                pk.x = pack2(f0.x, f0.y); pk.y = pack2(f0.z, f0.w);
                pk.z = pack2(f1.x, f1.y); pk.w = pack2(f1.z, f1.w);
                *(uint4*)(&As[row * BK + sch * 8]) = pk;
            }
            // --- B ---
            {
                const float4* src = (const float4*)(wbase + (size_t)(n0 + row) * DIN + kof + ch * 8);
                float4 f0 = src[0], f1 = src[1];
                uint4 pk;
                pk.x = pack2(f0.x, f0.y); pk.y = pack2(f0.z, f0.w);
                pk.z = pack2(f1.x, f1.y); pk.w = pack2(f1.z, f1.w);
                *(uint4*)(&Bs[row * BK + sch * 8]) = pk;
            }
        }
        __syncthreads();
        // Compute: 2 k-slices x 16 MFMA
        #pragma unroll
        for (int ks = 0; ks < 2; ++ks) {
            bf16x8 a[4], b[4];
            #pragma unroll
            for (int i = 0; i < 4; ++i) {
                int ra  = wm + i * 16 + lr;
                int ca  = (ks * 4 + g) ^ (ra & 7);
                a[i] = *(const bf16x8*)(&As[ra * BK + ca * 8]);
                int rb  = wn + i * 16 + lr;
                int cb  = (ks * 4 + g) ^ (rb & 7);
                b[i] = *(const bf16x8*)(&Bs[rb * BK + cb * 8]);
            }
            #pragma unroll
            for (int i = 0; i < 4; ++i)
                #pragma unroll
                for (int j = 0; j < 4; ++j)
                    acc[i][j] = __builtin_amdgcn_mfma_f32_16x16x32_bf16(a[i], b[j], acc[i][j], 0, 0, 0);
        }
    }

    // Epilogue: out[token] += gate * y  (each token gets exactly TOPK contributions)
    #pragma unroll
    for (int i = 0; i < 4; ++i) {
        #pragma unroll
        for (int j2 = 0; j2 < 4; ++j2) {
            int lrow = wm + i * 16 + g * 4 + j2;   // local sorted-row of this acc reg
            if (lrow < cnt) {
                int   p  = s_tok[lrow];
                float gf = s_gate[lrow];
                float* orow = out + (size_t)(p >> 1) * DOUT + n0 + wn;
                #pragma unroll
                for (int nf = 0; nf < 4; ++nf)
                    atomicAdd(orow + nf * 16 + lr, gf * acc[i][nf][j2]);
            }
        }
    }
}

extern "C" void kernel_launch(void* const* d_in, const int* in_sizes, int n_in,
                              void* d_out, int out_size, void* d_ws, size_t ws_size,
                              hipStream_t stream) {
    const float* inputs  = (const float*)d_in[0];
    const float* weight  = (const float*)d_in[1];
    // d_in[2] = k (scalar), d_in[3] = sorted_expert_idxs (unused; offsets suffice)
    const int*   ssi     = (const int*)d_in[4];
    // d_in[5] = padded_block_idxs (dummy)
    const int*   eoff    = (const int*)d_in[6];
    const float* gates   = (const float*)d_in[7];
    float* out = (float*)d_out;

    hipMemsetAsync(out, 0, (size_t)out_size * sizeof(float), stream);
    dim3 grid(DOUT / BN, MAXMT);
    moe_gemm<<<grid, 256, 0, stream>>>(inputs, weight, ssi, eoff, gates, out);
}

// Round 2
// 110.955 us; speedup vs baseline: 1.1882x; 1.1882x over previous
//
#include <hip/hip_runtime.h>
#include <hip/hip_bf16.h>

// Problem constants (fixed shapes from the reference)
#define DIN   2048
#define DOUT  2048
#define NTOK  2048
#define NE    8
#define TOPK  2
#define NK    (NTOK*TOPK)   // 4096 flat (token,slot) rows
#define BM    128
#define BN    128
#define BK    64
#define KTILES (DIN/BK)     // 32
#define MAXMT  (NK/BM + NE) // 40 worst-case M-tiles across ragged experts

typedef __attribute__((ext_vector_type(8))) short bf16x8;
typedef __attribute__((ext_vector_type(4))) float f32x4;

// fp32 -> bf16 pair pack: round-half-away (add 0x8000 to bit pattern), then
// v_perm_b32 grabs the two high halves in one instruction. 3 VALU/pair.
__device__ inline unsigned pack2rn(float a, float b) {
    union { float f; unsigned u; } x, y; x.f = a; y.f = b;
    return __builtin_amdgcn_perm(y.u + 0x8000u, x.u + 0x8000u, 0x07060302u);
}

// Grouped GEMM over sorted-by-expert rows. One block = 128 sorted rows x 128 d_out cols.
// Register-prefetch pipeline: tile k+1's global loads issue during tile k's MFMA.
__global__ __launch_bounds__(256, 3) void moe_gemm(
    const float* __restrict__ inputs,        // [NTOK, DIN]
    const float* __restrict__ weight,        // [NE, DOUT, DIN]
    const int*   __restrict__ sorted_scattered_idxs, // [NK]
    const int*   __restrict__ expert_offsets,        // [NE] cumsum ends
    const float* __restrict__ gates,         // [NTOK, TOPK] flat
    float*       __restrict__ out)           // [NTOK, DOUT]
{
    __shared__ unsigned short As[BM * BK];   // XOR-swizzled bf16 tiles
    __shared__ unsigned short Bs[BN * BK];
    __shared__ int   s_tok[BM];
    __shared__ float s_gate[BM];

    const int mt = blockIdx.y;
    const int n0 = blockIdx.x * BN;

    // Resolve this M-tile: which expert, which sorted-row range
    int e = -1, m0 = 0, cnt = 0;
    {
        int acc = 0, prev = 0;
        for (int i = 0; i < NE; ++i) {
            int end = expert_offsets[i];
            int c = end - prev;
            int t = (c + BM - 1) / BM;
            if (mt < acc + t) {
                e = i; m0 = prev + (mt - acc) * BM;
                cnt = end - m0; if (cnt > BM) cnt = BM;
                break;
            }
            acc += t; prev = end;
        }
    }
    if (e < 0) return;   // tail blocks beyond the real tile count

    const int tid = threadIdx.x;
    if (tid < BM) {
        int idx = (tid < cnt) ? (m0 + tid) : m0;   // clamp ragged rows to a valid gather
        int p = sorted_scattered_idxs[idx];        // flat slot id = token*TOPK + slot
        s_tok[tid]  = p;
        s_gate[tid] = gates[p];
    }
    __syncthreads();

    // ---- hoisted staging geometry (constant per thread) ----
    const int ch  = tid & 7;             // 8-float chunk within a 64-wide row
    const int r0  = tid >> 3;            // base row; thread stages rows r0+32*i
    const int sch = ch ^ (r0 & 7);       // 16B-chunk XOR swizzle (r&7 == r0&7 for all i)

    const float* wbase = weight + (size_t)e * DOUT * DIN;
    const float* ap[4];
    const float* bp[4];
    #pragma unroll
    for (int i = 0; i < 4; ++i) {
        int r = r0 + 32 * i;
        ap[i] = inputs + (size_t)(s_tok[r] >> 1) * DIN + ch * 8;
        bp[i] = wbase + (size_t)(n0 + r) * DIN + ch * 8;
    }
    unsigned short* aw = &As[r0 * BK + sch * 8];   // row stride 32*BK els between i's
    unsigned short* bw = &Bs[r0 * BK + sch * 8];

    const int wid = tid >> 6, lane = tid & 63;
    const int wm = (wid >> 1) * 64, wn = (wid & 1) * 64;  // 2x2 waves, 64x64 each
    const int g  = lane >> 4, lr = lane & 15;

    f32x4 acc[4][4];
    #pragma unroll
    for (int i = 0; i < 4; ++i)
        #pragma unroll
        for (int j = 0; j < 4; ++j) acc[i][j] = (f32x4)0.0f;

    // ---- prologue: load K-tile 0 into registers ----
    float4 pa[4][2], pb[4][2];
    #pragma unroll
    for (int i = 0; i < 4; ++i) {
        pa[i][0] = *(const float4*)(ap[i] + 0);
        pa[i][1] = *(const float4*)(ap[i] + 4);
        pb[i][0] = *(const float4*)(bp[i] + 0);
        pb[i][1] = *(const float4*)(bp[i] + 4);
    }

    for (int kt = 0; kt < KTILES; ++kt) {
        __syncthreads();   // previous iter's LDS readers done before overwrite
        // cvt current registers -> bf16 LDS (cheap pack: 12 VALU per 8 floats)
        #pragma unroll
        for (int i = 0; i < 4; ++i) {
            uint4 va, vb;
            va.x = pack2rn(pa[i][0].x, pa[i][0].y);
            va.y = pack2rn(pa[i][0].z, pa[i][0].w);
            va.z = pack2rn(pa[i][1].x, pa[i][1].y);
            va.w = pack2rn(pa[i][1].z, pa[i][1].w);
            *(uint4*)(aw + i * 32 * BK) = va;
            vb.x = pack2rn(pb[i][0].x, pb[i][0].y);
            vb.y = pack2rn(pb[i][0].z, pb[i][0].w);
            vb.z = pack2rn(pb[i][1].x, pb[i][1].y);
            vb.w = pack2rn(pb[i][1].z, pb[i][1].w);
            *(uint4*)(bw + i * 32 * BK) = vb;
        }
        __syncthreads();
        // issue next K-tile's loads now; they fly during the MFMA phase
        if (kt + 1 < KTILES) {
            const int kof = (kt + 1) * BK;
            #pragma unroll
            for (int i = 0; i < 4; ++i) {
                pa[i][0] = *(const float4*)(ap[i] + kof);
                pa[i][1] = *(const float4*)(ap[i] + kof + 4);
                pb[i][0] = *(const float4*)(bp[i] + kof);
                pb[i][1] = *(const float4*)(bp[i] + kof + 4);
            }
        }
        // compute: 2 k-slices x 16 MFMA
        #pragma unroll
        for (int ks = 0; ks < 2; ++ks) {
            bf16x8 a[4], b[4];
            #pragma unroll
            for (int i = 0; i < 4; ++i) {
                int ra = wm + i * 16 + lr;
                int ca = (ks * 4 + g) ^ (ra & 7);
                a[i] = *(const bf16x8*)(&As[ra * BK + ca * 8]);
                int rb = wn + i * 16 + lr;
                int cb = (ks * 4 + g) ^ (rb & 7);
                b[i] = *(const bf16x8*)(&Bs[rb * BK + cb * 8]);
            }
            #pragma unroll
            for (int i = 0; i < 4; ++i)
                #pragma unroll
                for (int j = 0; j < 4; ++j)
                    acc[i][j] = __builtin_amdgcn_mfma_f32_16x16x32_bf16(a[i], b[j], acc[i][j], 0, 0, 0);
        }
    }

    // Epilogue: out[token] += gate * y  (each token gets exactly TOPK contributions)
    #pragma unroll
    for (int i = 0; i < 4; ++i) {
        #pragma unroll
        for (int j2 = 0; j2 < 4; ++j2) {
            int lrow = wm + i * 16 + g * 4 + j2;   // local sorted-row of this acc reg
            if (lrow < cnt) {
                int   p  = s_tok[lrow];
                float gf = s_gate[lrow];
                float* orow = out + (size_t)(p >> 1) * DOUT + n0 + wn;
                #pragma unroll
                for (int nf = 0; nf < 4; ++nf)
                    atomicAdd(orow + nf * 16 + lr, gf * acc[i][nf][j2]);
            }
        }
    }
}

extern "C" void kernel_launch(void* const* d_in, const int* in_sizes, int n_in,
                              void* d_out, int out_size, void* d_ws, size_t ws_size,
                              hipStream_t stream) {
    const float* inputs  = (const float*)d_in[0];
    const float* weight  = (const float*)d_in[1];
    // d_in[2] = k (scalar), d_in[3] = sorted_expert_idxs (unused; offsets suffice)
    const int*   ssi     = (const int*)d_in[4];
    // d_in[5] = padded_block_idxs (dummy)
    const int*   eoff    = (const int*)d_in[6];
    const float* gates   = (const float*)d_in[7];
    float* out = (float*)d_out;

    hipMemsetAsync(out, 0, (size_t)out_size * sizeof(float), stream);
    dim3 grid(DOUT / BN, MAXMT);
    moe_gemm<<<grid, 256, 0, stream>>>(inputs, weight, ssi, eoff, gates, out);
}